// Round 4
// baseline (93.384 us; speedup 1.0000x reference)
//
#include <hip/hip_runtime.h>

// Problem constants (from reference): B=32, L=4096, D=128, N=5, V=128
constexpr int Bn = 32;
constexpr int Ln = 4096;
constexpr int Dn = 128;
constexpr int Vn = 128;
constexpr int N1 = 4;  // N - 1 context slots

typedef float vfloat4 __attribute__((ext_vector_type(4)));  // native vec for nontemporal builtins

// Kernel A0: transpose W (V x N1*D) -> Wt (N1*D x V) so table-build reads coalesce.
// 65536 elements, one thread each; writes coalesced (v fastest), reads hit L2 (256 KiB).
__global__ void transpose_w_kernel(const float* __restrict__ W, float* __restrict__ Wt) {
    const int tid = blockIdx.x * 256 + threadIdx.x;
    const int v = tid & 127;
    const int f = tid >> 7;          // 0..511
    Wt[f * Vn + v] = W[v * (Dn * N1) + f];
}

// Kernel A1: T[k*128+t][v] = sum_d emb[t][d] * Wt[k*D+d][v]  (+ bias[v] for k==0)
// grid: 512 blocks (one per (k,t)), 128 threads = 32 v-quads x 4 d-groups.
// Wt loads: lanes 0..31 read consecutive float4s (512 B contiguous) -> fully coalesced.
__global__ void build_table_kernel(const float* __restrict__ emb,
                                   const float* __restrict__ Wt,
                                   const float* __restrict__ bias,
                                   float* __restrict__ T) {
    const int kt = blockIdx.x;        // k*128 + t
    const int k  = kt >> 7;
    const int t  = kt & 127;
    const int v4 = threadIdx.x & 31;  // v-quad index
    const int dg = threadIdx.x >> 5;  // d-group 0..3 (each covers 32 d)

    __shared__ float  e_s[Dn];
    __shared__ float4 red[4][32];

    if (threadIdx.x < 32)
        ((float4*)e_s)[threadIdx.x] = ((const float4*)(emb + t * Dn))[threadIdx.x];
    __syncthreads();

    const float4* Wt4 = (const float4*)Wt;  // [512][32] float4
    float4 acc = make_float4(0.f, 0.f, 0.f, 0.f);
#pragma unroll
    for (int d = 0; d < 32; ++d) {
        const int f = k * Dn + dg * 32 + d;
        const float4 wv = Wt4[f * 32 + v4];
        const float  ev = e_s[dg * 32 + d];
        acc.x += ev * wv.x; acc.y += ev * wv.y;
        acc.z += ev * wv.z; acc.w += ev * wv.w;
    }

    red[dg][v4] = acc;
    __syncthreads();

    if (dg == 0) {
        const float4 a = red[0][v4], b = red[1][v4], c = red[2][v4], d4 = red[3][v4];
        float4 s;
        s.x = a.x + b.x + c.x + d4.x;
        s.y = a.y + b.y + c.y + d4.y;
        s.z = a.z + b.z + c.z + d4.z;
        s.w = a.w + b.w + c.w + d4.w;
        if (k == 0) {  // fold bias into slot-0 table
            const float4 bv = ((const float4*)bias)[v4];
            s.x += bv.x; s.y += bv.y; s.z += bv.z; s.w += bv.w;
        }
        ((float4*)T)[kt * 32 + v4] = s;
    }
}

// Kernel B (unchanged from R3): out[b,j,v] = sum_k T'[k][x[b,j-4+k]][v];
// j<4 rows are bias-only. Each thread: 4 consecutive positions x one float4 of v.
__global__ void __launch_bounds__(256)
ngram_logits_kernel(const int* __restrict__ x,
                    const float* __restrict__ T,
                    const float* __restrict__ bias,
                    float* __restrict__ out) {
    const int tid     = blockIdx.x * blockDim.x + threadIdx.x;
    const int vq      = tid & 31;          // v / 4
    const int g       = tid >> 5;          // position group
    const int basepos = g << 2;            // first of 4 positions (4-aligned)
    const int j0      = basepos & (Ln - 1);

    vfloat4* outq = (vfloat4*)out;

    if (j0 == 0) {
        const vfloat4 bv = ((const vfloat4*)bias)[vq];
#pragma unroll
        for (int i = 0; i < 4; ++i)
            __builtin_nontemporal_store(bv, &outq[(size_t)(basepos + i) * 32 + vq]);
        return;
    }

    const int4 xa = *(const int4*)(x + basepos - 4);
    const int4 xb = *(const int4*)(x + basepos);
    int w[7] = {xa.x, xa.y, xa.z, xa.w, xb.x, xb.y, xb.z};

    const vfloat4* Tq = (const vfloat4*)T;  // [4][128][32] vfloat4
    vfloat4 acc[4];
#pragma unroll
    for (int i = 0; i < 4; ++i) {
        vfloat4 a = Tq[(size_t)(0 * Vn + w[i + 0]) * 32 + vq];
#pragma unroll
        for (int k = 1; k < N1; ++k) {
            a += Tq[(size_t)(k * Vn + w[i + k]) * 32 + vq];
        }
        acc[i] = a;
    }

#pragma unroll
    for (int i = 0; i < 4; ++i)
        __builtin_nontemporal_store(acc[i], &outq[(size_t)(basepos + i) * 32 + vq]);
}

extern "C" void kernel_launch(void* const* d_in, const int* in_sizes, int n_in,
                              void* d_out, int out_size, void* d_ws, size_t ws_size,
                              hipStream_t stream) {
    const int*   x    = (const int*)d_in[0];    // (B, L) int32
    const float* emb  = (const float*)d_in[1];  // (V, D) fp32
    const float* W    = (const float*)d_in[2];  // (V, D*(N-1)) fp32
    const float* bias = (const float*)d_in[3];  // (V,) fp32
    float*       out  = (float*)d_out;          // (B, L, V) fp32

    float* T  = (float*)d_ws;                   // (4,128,128) fp32 = 256 KiB
    float* Wt = (float*)d_ws + (N1 * Vn * Vn);  // (512,128) fp32 = 256 KiB

    transpose_w_kernel<<<(N1 * Dn * Vn) / 256, 256, 0, stream>>>(W, Wt);
    build_table_kernel<<<N1 * Vn, Vn, 0, stream>>>(emb, Wt, bias, T);

    const int total_threads = (Bn * Ln / 4) * (Vn / 4);  // 1,048,576
    const int block = 256;
    ngram_logits_kernel<<<total_threads / block, block, 0, stream>>>(x, T, bias, out);
}